// Round 1
// baseline (870.416 us; speedup 1.0000x reference)
//
#include <hip/hip_runtime.h>
#include <stdint.h>

#define B_ 2
#define S_ 2048
#define HID_ 2048
#define H_ 16
#define D_ 128

typedef __bf16 bf16;
typedef __bf16 bf16x8 __attribute__((ext_vector_type(8)));
typedef __bf16 bf16x4 __attribute__((ext_vector_type(4)));
typedef float floatx4 __attribute__((ext_vector_type(4)));

#define MFMA16(a, b, c) __builtin_amdgcn_mfma_f32_16x16x32_bf16(a, b, c, 0, 0, 0)

__device__ __forceinline__ void gload_lds16(const bf16* g, bf16* l) {
  __builtin_amdgcn_global_load_lds(
      (const __attribute__((address_space(1))) uint32_t*)g,
      (__attribute__((address_space(3))) uint32_t*)l, 16, 0, 0);
}

// ---------------- cast fp32 -> bf16 (flat) ----------------
__global__ __launch_bounds__(256) void cast_bf16_k(const float* __restrict__ in,
                                                   bf16* __restrict__ out) {
  size_t i = ((size_t)blockIdx.x * 256 + threadIdx.x) * 4;
  float4 v = *(const float4*)(in + i);
  bf16x4 o;
  o[0] = (bf16)v.x; o[1] = (bf16)v.y; o[2] = (bf16)v.z; o[3] = (bf16)v.w;
  *(bf16x4*)(out + i) = o;
}

// ---------------- transpose + cast: in (R x C) f32 -> out (C x R) bf16 ----------------
__global__ __launch_bounds__(256) void transpose_cast_k(const float* __restrict__ in,
                                                        bf16* __restrict__ out,
                                                        int R, int C) {
  __shared__ bf16 tile[64][65];
  int tc = blockIdx.x * 64, tr = blockIdx.y * 64;
  int t = threadIdx.x;
  int c = t & 63, r0 = t >> 6;
  const float* ip = in + (size_t)(tr + r0) * C + tc + c;
#pragma unroll
  for (int i = 0; i < 16; i++)
    tile[r0 + i * 4][c] = (bf16)ip[(size_t)i * 4 * C];
  __syncthreads();
  int n = t >> 2, ch = t & 3;
  bf16x8 v0, v1;
#pragma unroll
  for (int j = 0; j < 8; j++) {
    v0[j] = tile[ch * 16 + j][n];
    v1[j] = tile[ch * 16 + 8 + j][n];
  }
  bf16* op = out + (size_t)(tc + n) * R + tr + ch * 16;
  *(bf16x8*)op = v0;
  *(bf16x8*)(op + 8) = v1;
}

// ---------------- GEMM: C[M,N] = A[M,K] * Bt[N,K]^T   (m97 structure) ----------------
template <typename OutT>
__global__ __launch_bounds__(256) void gemm_bt_k(const bf16* __restrict__ A,
                                                 const bf16* __restrict__ Bt,
                                                 OutT* __restrict__ C,
                                                 int M, int N, int K) {
  __shared__ __align__(16) bf16 As[4096];  // 128 rows x 32 k
  __shared__ __align__(16) bf16 Bs[4096];  // 128 n-rows x 32 k
  const int t = threadIdx.x;
  const int w = t >> 6, l = t & 63;
  const int quad = l >> 4, ln = l & 15;
  const int wm = w >> 1, wn = w & 1;
  const int m0 = blockIdx.x * 128, n0 = blockIdx.y * 128;

  floatx4 acc[4][4] = {};

  // staging: chunk c = 2w+i covers tile rows [16c,16c+16); lane l -> row 16c + l/4, koff (l&3)*8 elems
  const int srow = w * 32 + (l >> 2);
  const int skoff = (l & 3) * 8;
  const bf16* Ag = A + (size_t)(m0 + srow) * K + skoff;
  const bf16* Bg = Bt + (size_t)(n0 + srow) * K + skoff;
  bf16* AsW0 = As + (2 * w + 0) * 512;
  bf16* AsW1 = As + (2 * w + 1) * 512;
  bf16* BsW0 = Bs + (2 * w + 0) * 512;
  bf16* BsW1 = Bs + (2 * w + 1) * 512;
  const size_t rstep = (size_t)16 * K;

  for (int kt = 0; kt < K; kt += 32) {
    gload_lds16(Ag + kt, AsW0);
    gload_lds16(Ag + kt + rstep, AsW1);
    gload_lds16(Bg + kt, BsW0);
    gload_lds16(Bg + kt + rstep, BsW1);
    __syncthreads();
    bf16x8 af[4], bfr[4];
#pragma unroll
    for (int mt = 0; mt < 4; mt++)
      af[mt] = *(const bf16x8*)(As + (wm * 64 + mt * 16 + ln) * 32 + quad * 8);
#pragma unroll
    for (int nt = 0; nt < 4; nt++)
      bfr[nt] = *(const bf16x8*)(Bs + (wn * 64 + nt * 16 + ln) * 32 + quad * 8);
#pragma unroll
    for (int mt = 0; mt < 4; mt++)
#pragma unroll
      for (int nt = 0; nt < 4; nt++)
        acc[mt][nt] = MFMA16(af[mt], bfr[nt], acc[mt][nt]);
    __syncthreads();
  }

#pragma unroll
  for (int mt = 0; mt < 4; mt++)
#pragma unroll
    for (int nt = 0; nt < 4; nt++) {
      int row = m0 + wm * 64 + mt * 16 + quad * 4;
      int col = n0 + wn * 64 + nt * 16 + ln;
      OutT* cp = C + (size_t)row * N + col;
#pragma unroll
      for (int r = 0; r < 4; r++)
        cp[(size_t)r * N] = (OutT)acc[mt][nt][r];
    }
}

// ---------------- qkv split + xPos rotary + V transpose ----------------
__global__ __launch_bounds__(256) void qkv_transform_k(const bf16* __restrict__ qkv,
                                                       const int* __restrict__ pos_ids,
                                                       bf16* __restrict__ Q,
                                                       bf16* __restrict__ Kk,
                                                       bf16* __restrict__ Vt) {
  __shared__ bf16 vtile[128 * 65];
  int blk = blockIdx.x;
  int st = blk & 31;
  int h = (blk >> 5) & 15;
  int b = blk >> 9;
  int t = threadIdx.x;
  int sl = t >> 2, dg = t & 3;  // 64 s-rows x 4 d-groups of 32
  int s = st * 64 + sl;
  float tp = (float)pos_ids[b * S_ + s];

  const bf16* base = qkv + (size_t)(b * S_ + s) * (3 * HID_) + h * (3 * D_) + dg * 32;
  bf16 qv[32], kv[32], vv[32];
#pragma unroll
  for (int i = 0; i < 4; i++) ((bf16x8*)qv)[i] = *(const bf16x8*)(base + i * 8);
#pragma unroll
  for (int i = 0; i < 4; i++) ((bf16x8*)kv)[i] = *(const bf16x8*)(base + D_ + i * 8);
#pragma unroll
  for (int i = 0; i < 4; i++) ((bf16x8*)vv)[i] = *(const bf16x8*)(base + 2 * D_ + i * 8);

  if (dg == 0) {  // rotary covers dims 0..31 exactly
    float power = (tp - 1024.0f) * (1.0f / 512.0f);
#pragma unroll
    for (int i = 0; i < 16; i++) {
      float inv_freq = powf(10000.0f, -(float)i * (1.0f / 16.0f));
      float fr = tp * inv_freq;
      float cs = cosf(fr), sn = sinf(fr);
      float scl = ((float)(2 * i) + 12.8f) * (1.0f / 44.8f);
      float sc = powf(scl, power);
      float cq = cs * sc, sq = sn * sc;
      float ck = cs / sc, sk = sn / sc;
      float q1 = (float)qv[i], q2 = (float)qv[i + 16];
      float k1 = (float)kv[i], k2 = (float)kv[i + 16];
      qv[i] = (bf16)(q1 * cq - q2 * sq);
      qv[i + 16] = (bf16)(q2 * cq + q1 * sq);
      kv[i] = (bf16)(k1 * ck - k2 * sk);
      kv[i + 16] = (bf16)(k2 * ck + k1 * sk);
    }
  }
  size_t qoff = (size_t)((b * H_ + h) * S_ + s) * D_ + dg * 32;
#pragma unroll
  for (int i = 0; i < 4; i++) *(bf16x8*)(Q + qoff + i * 8) = ((bf16x8*)qv)[i];
#pragma unroll
  for (int i = 0; i < 4; i++) *(bf16x8*)(Kk + qoff + i * 8) = ((bf16x8*)kv)[i];

  // V transpose through LDS -> Vt[b][h][d][s]
#pragma unroll
  for (int i = 0; i < 32; i++) vtile[(dg * 32 + i) * 65 + sl] = vv[i];
  __syncthreads();
  int d = t >> 1, half = t & 1;
  size_t voff = (size_t)((b * H_ + h) * D_ + d) * S_ + st * 64 + half * 32;
#pragma unroll
  for (int i = 0; i < 4; i++) {
    bf16x8 tv;
#pragma unroll
    for (int j = 0; j < 8; j++) tv[j] = vtile[d * 65 + half * 32 + i * 8 + j];
    *(bf16x8*)(Vt + voff + i * 8) = tv;
  }
}

// ---------------- flash attention: 1 block = (b, h, 64 q rows), 4 waves x 16 rows ----------------
__global__ __launch_bounds__(256) void flash_k(const bf16* __restrict__ Q,
                                               const bf16* __restrict__ K,
                                               const bf16* __restrict__ Vt,
                                               const float* __restrict__ amask,
                                               bf16* __restrict__ O) {
  __shared__ __align__(16) bf16 pbuf[4][1024];  // per-wave P (16x64)
  int blk = blockIdx.x;
  int qt = 31 - (blk & 31);  // longest tiles first
  int h = (blk >> 5) & 15;
  int b = blk >> 9;
  int t = threadIdx.x;
  int w = t >> 6, l = t & 63;
  int quad = l >> 4, ln = l & 15;
  int q0 = qt * 64;
  int qrow = q0 + w * 16;

  const bf16* Qp = Q + (size_t)((b * H_ + h) * S_ + qrow + ln) * D_;
  const bf16* Kbase = K + (size_t)(b * H_ + h) * S_ * D_;
  const bf16* Vbase = Vt + (size_t)(b * H_ + h) * D_ * S_;
  const float* mbase = amask + (size_t)b * S_;

  bf16x8 qf[4];
#pragma unroll
  for (int ks = 0; ks < 4; ks++)
    qf[ks] = *(const bf16x8*)(Qp + ks * 32 + quad * 8);

  floatx4 o_acc[8] = {};
  float m_i[4] = {-1e30f, -1e30f, -1e30f, -1e30f};
  float l_i[4] = {0.f, 0.f, 0.f, 0.f};
  bf16* pw = pbuf[w];
  const float scale = 0.08838834764831845f;  // 1/sqrt(128)

  int ktiles = qt + 1;
  for (int kt = 0; kt < ktiles; kt++) {
    int kv0 = kt * 64;
    float sv[4][4];
#pragma unroll
    for (int nt = 0; nt < 4; nt++) {
      const bf16* kp = Kbase + (size_t)(kv0 + nt * 16 + ln) * D_ + quad * 8;
      floatx4 acc = {};
#pragma unroll
      for (int ks = 0; ks < 4; ks++)
        acc = MFMA16(qf[ks], *(const bf16x8*)(kp + ks * 32), acc);
      int col = kv0 + nt * 16 + ln;
      float am = mbase[col];
#pragma unroll
      for (int r = 0; r < 4; r++) {
        float v = acc[r] * scale + am;
        if (col > qrow + quad * 4 + r) v = -3.0e38f;  // causal
        sv[nt][r] = v;
      }
    }
#pragma unroll
    for (int r = 0; r < 4; r++) {
      float mx = fmaxf(fmaxf(sv[0][r], sv[1][r]), fmaxf(sv[2][r], sv[3][r]));
#pragma unroll
      for (int off = 1; off < 16; off <<= 1)
        mx = fmaxf(mx, __shfl_xor(mx, off, 64));
      float mnew = fmaxf(m_i[r], mx);
      float sum = 0.f;
#pragma unroll
      for (int nt = 0; nt < 4; nt++) {
        float p = __expf(sv[nt][r] - mnew);
        sv[nt][r] = p;
        sum += p;
      }
#pragma unroll
      for (int off = 1; off < 16; off <<= 1)
        sum += __shfl_xor(sum, off, 64);
      float alpha = __expf(m_i[r] - mnew);
      l_i[r] = l_i[r] * alpha + sum;
      m_i[r] = mnew;
#pragma unroll
      for (int dt = 0; dt < 8; dt++) o_acc[dt][r] *= alpha;
    }
    // P: C-layout -> A-layout through LDS (m120 pattern)
#pragma unroll
    for (int nt = 0; nt < 4; nt++)
#pragma unroll
      for (int r = 0; r < 4; r++)
        pw[(quad * 4 + r) * 64 + nt * 16 + ln] = (bf16)sv[nt][r];
    __syncthreads();
    bf16x8 pf0 = *(const bf16x8*)(pw + ln * 64 + quad * 8);
    bf16x8 pf1 = *(const bf16x8*)(pw + ln * 64 + 32 + quad * 8);
#pragma unroll
    for (int dt = 0; dt < 8; dt++) {
      const bf16* vp = Vbase + (size_t)(dt * 16 + ln) * S_ + kv0 + quad * 8;
      floatx4 acc = o_acc[dt];
      acc = MFMA16(pf0, *(const bf16x8*)vp, acc);
      acc = MFMA16(pf1, *(const bf16x8*)(vp + 32), acc);
      o_acc[dt] = acc;
    }
    __syncthreads();
  }

#pragma unroll
  for (int r = 0; r < 4; r++) {
    float inv_l = 1.0f / l_i[r];
    int qq = qrow + quad * 4 + r;
    bf16* op = O + (size_t)(b * S_ + qq) * HID_ + h * D_ + ln;
#pragma unroll
    for (int dt = 0; dt < 8; dt++)
      op[dt * 16] = (bf16)(o_acc[dt][r] * inv_l);
  }
}

// ---------------- launch ----------------
extern "C" void kernel_launch(void* const* d_in, const int* in_sizes, int n_in,
                              void* d_out, int out_size, void* d_ws, size_t ws_size,
                              hipStream_t stream) {
  const float* hidden = (const float*)d_in[0];
  const float* amask = (const float*)d_in[1];
  const float* Wqkv = (const float*)d_in[2];
  const float* Wdense = (const float*)d_in[3];
  const int* posids = (const int*)d_in[4];
  float* out = (float*)d_out;
  char* ws = (char*)d_ws;

  // workspace layout (regions reused across phases; total 125,829,120 B):
  //  [0,               8.0M)  wdense_t (2048x2048 bf16)
  //  [8,388,608,      58.7M)  qkv bf16 (4096 x 6144)
  //  [58,720,256,     75.5M)  hs bf16  -> (after GEMM1) attn_out bf16
  //  [75,497,472,    100.7M)  wqkv_t (6144x2048 bf16) -> (after GEMM1) Q, then K starts at 92.3M
  //  [109,051,904,   125.8M)  Vt bf16
  bf16* wdT = (bf16*)(ws + 0);
  bf16* qkv = (bf16*)(ws + 8388608ull);
  bf16* hsb = (bf16*)(ws + 58720256ull);
  bf16* attn = (bf16*)(ws + 58720256ull);
  bf16* wqT = (bf16*)(ws + 75497472ull);
  bf16* Qb = (bf16*)(ws + 75497472ull);
  bf16* Kb = (bf16*)(ws + 92274688ull);
  bf16* Vtb = (bf16*)(ws + 109051904ull);

  cast_bf16_k<<<8192, 256, 0, stream>>>(hidden, hsb);
  transpose_cast_k<<<dim3(96, 32), 256, 0, stream>>>(Wqkv, wqT, 2048, 6144);
  transpose_cast_k<<<dim3(32, 32), 256, 0, stream>>>(Wdense, wdT, 2048, 2048);
  gemm_bt_k<bf16><<<dim3(32, 48), 256, 0, stream>>>(hsb, wqT, qkv, 4096, 6144, 2048);
  qkv_transform_k<<<1024, 256, 0, stream>>>(qkv, posids, Qb, Kb, Vtb);
  flash_k<<<1024, 256, 0, stream>>>(Qb, Kb, Vtb, amask, attn);
  gemm_bt_k<float><<<dim3(32, 16), 256, 0, stream>>>(attn, wdT, out, 4096, 2048, 2048);
}

// Round 2
// 602.387 us; speedup vs baseline: 1.4449x; 1.4449x over previous
//
#include <hip/hip_runtime.h>
#include <stdint.h>

#define B_ 2
#define S_ 2048
#define HID_ 2048
#define H_ 16
#define D_ 128

typedef __bf16 bf16;
typedef __bf16 bf16x8 __attribute__((ext_vector_type(8)));
typedef __bf16 bf16x4 __attribute__((ext_vector_type(4)));
typedef float floatx4 __attribute__((ext_vector_type(4)));

#define MFMA16(a, b, c) __builtin_amdgcn_mfma_f32_16x16x32_bf16(a, b, c, 0, 0, 0)

__device__ __forceinline__ void gload_lds16(const bf16* g, bf16* l) {
  __builtin_amdgcn_global_load_lds(
      (const __attribute__((address_space(1))) uint32_t*)g,
      (__attribute__((address_space(3))) uint32_t*)l, 16, 0, 0);
}

// ---------------- cast fp32 -> bf16 (flat) ----------------
__global__ __launch_bounds__(256) void cast_bf16_k(const float* __restrict__ in,
                                                   bf16* __restrict__ out) {
  size_t i = ((size_t)blockIdx.x * 256 + threadIdx.x) * 4;
  float4 v = *(const float4*)(in + i);
  bf16x4 o;
  o[0] = (bf16)v.x; o[1] = (bf16)v.y; o[2] = (bf16)v.z; o[3] = (bf16)v.w;
  *(bf16x4*)(out + i) = o;
}

// ---------------- transpose + cast: in (R x C) f32 -> out (C x R) bf16 ----------------
__global__ __launch_bounds__(256) void transpose_cast_k(const float* __restrict__ in,
                                                        bf16* __restrict__ out,
                                                        int R, int C) {
  __shared__ bf16 tile[64][65];
  int tc = blockIdx.x * 64, tr = blockIdx.y * 64;
  int t = threadIdx.x;
  int c = t & 63, r0 = t >> 6;
  const float* ip = in + (size_t)(tr + r0) * C + tc + c;
#pragma unroll
  for (int i = 0; i < 16; i++)
    tile[r0 + i * 4][c] = (bf16)ip[(size_t)i * 4 * C];
  __syncthreads();
  int n = t >> 2, ch = t & 3;
  bf16x8 v0, v1;
#pragma unroll
  for (int j = 0; j < 8; j++) {
    v0[j] = tile[ch * 16 + j][n];
    v1[j] = tile[ch * 16 + 8 + j][n];
  }
  bf16* op = out + (size_t)(tc + n) * R + tr + ch * 16;
  *(bf16x8*)op = v0;
  *(bf16x8*)(op + 8) = v1;
}

// ---------------- GEMM: C[M,N] = A[M,K] * Bt[N,K]^T   (m97 structure) ----------------
template <typename OutT>
__global__ __launch_bounds__(256) void gemm_bt_k(const bf16* __restrict__ A,
                                                 const bf16* __restrict__ Bt,
                                                 OutT* __restrict__ C,
                                                 int M, int N, int K) {
  __shared__ __align__(16) bf16 As[4096];  // 128 rows x 32 k
  __shared__ __align__(16) bf16 Bs[4096];  // 128 n-rows x 32 k
  const int t = threadIdx.x;
  const int w = t >> 6, l = t & 63;
  const int quad = l >> 4, ln = l & 15;
  const int wm = w >> 1, wn = w & 1;
  const int m0 = blockIdx.x * 128, n0 = blockIdx.y * 128;

  floatx4 acc[4][4] = {};

  const int srow = w * 32 + (l >> 2);
  const int skoff = (l & 3) * 8;
  const bf16* Ag = A + (size_t)(m0 + srow) * K + skoff;
  const bf16* Bg = Bt + (size_t)(n0 + srow) * K + skoff;
  bf16* AsW0 = As + (2 * w + 0) * 512;
  bf16* AsW1 = As + (2 * w + 1) * 512;
  bf16* BsW0 = Bs + (2 * w + 0) * 512;
  bf16* BsW1 = Bs + (2 * w + 1) * 512;
  const size_t rstep = (size_t)16 * K;

  for (int kt = 0; kt < K; kt += 32) {
    gload_lds16(Ag + kt, AsW0);
    gload_lds16(Ag + kt + rstep, AsW1);
    gload_lds16(Bg + kt, BsW0);
    gload_lds16(Bg + kt + rstep, BsW1);
    __syncthreads();
    bf16x8 af[4], bfr[4];
#pragma unroll
    for (int mt = 0; mt < 4; mt++)
      af[mt] = *(const bf16x8*)(As + (wm * 64 + mt * 16 + ln) * 32 + quad * 8);
#pragma unroll
    for (int nt = 0; nt < 4; nt++)
      bfr[nt] = *(const bf16x8*)(Bs + (wn * 64 + nt * 16 + ln) * 32 + quad * 8);
#pragma unroll
    for (int mt = 0; mt < 4; mt++)
#pragma unroll
      for (int nt = 0; nt < 4; nt++)
        acc[mt][nt] = MFMA16(af[mt], bfr[nt], acc[mt][nt]);
    __syncthreads();
  }

#pragma unroll
  for (int mt = 0; mt < 4; mt++)
#pragma unroll
    for (int nt = 0; nt < 4; nt++) {
      int row = m0 + wm * 64 + mt * 16 + quad * 4;
      int col = n0 + wn * 64 + nt * 16 + ln;
      OutT* cp = C + (size_t)row * N + col;
#pragma unroll
      for (int r = 0; r < 4; r++)
        cp[(size_t)r * N] = (OutT)acc[mt][nt][r];
    }
}

// ---------------- qkv split + xPos rotary + V transpose ----------------
__global__ __launch_bounds__(256) void qkv_transform_k(const bf16* __restrict__ qkv,
                                                       const int* __restrict__ pos_ids,
                                                       bf16* __restrict__ Q,
                                                       bf16* __restrict__ Kk,
                                                       bf16* __restrict__ Vt) {
  __shared__ bf16 vtile[128 * 65];
  int blk = blockIdx.x;
  int st = blk & 31;
  int h = (blk >> 5) & 15;
  int b = blk >> 9;
  int t = threadIdx.x;
  int sl = t >> 2, dg = t & 3;
  int s = st * 64 + sl;
  float tp = (float)pos_ids[b * S_ + s];

  const bf16* base = qkv + (size_t)(b * S_ + s) * (3 * HID_) + h * (3 * D_) + dg * 32;
  bf16 qv[32], kv[32], vv[32];
#pragma unroll
  for (int i = 0; i < 4; i++) ((bf16x8*)qv)[i] = *(const bf16x8*)(base + i * 8);
#pragma unroll
  for (int i = 0; i < 4; i++) ((bf16x8*)kv)[i] = *(const bf16x8*)(base + D_ + i * 8);
#pragma unroll
  for (int i = 0; i < 4; i++) ((bf16x8*)vv)[i] = *(const bf16x8*)(base + 2 * D_ + i * 8);

  if (dg == 0) {  // rotary covers dims 0..31 exactly
    float power = (tp - 1024.0f) * (1.0f / 512.0f);
#pragma unroll
    for (int i = 0; i < 16; i++) {
      float inv_freq = powf(10000.0f, -(float)i * (1.0f / 16.0f));
      float fr = tp * inv_freq;
      float cs = cosf(fr), sn = sinf(fr);
      float scl = ((float)(2 * i) + 12.8f) * (1.0f / 44.8f);
      float sc = powf(scl, power);
      float cq = cs * sc, sq = sn * sc;
      float ck = cs / sc, sk = sn / sc;
      float q1 = (float)qv[i], q2 = (float)qv[i + 16];
      float k1 = (float)kv[i], k2 = (float)kv[i + 16];
      qv[i] = (bf16)(q1 * cq - q2 * sq);
      qv[i + 16] = (bf16)(q2 * cq + q1 * sq);
      kv[i] = (bf16)(k1 * ck - k2 * sk);
      kv[i + 16] = (bf16)(k2 * ck + k1 * sk);
    }
  }
  size_t qoff = (size_t)((b * H_ + h) * S_ + s) * D_ + dg * 32;
#pragma unroll
  for (int i = 0; i < 4; i++) *(bf16x8*)(Q + qoff + i * 8) = ((bf16x8*)qv)[i];
#pragma unroll
  for (int i = 0; i < 4; i++) *(bf16x8*)(Kk + qoff + i * 8) = ((bf16x8*)kv)[i];

#pragma unroll
  for (int i = 0; i < 32; i++) vtile[(dg * 32 + i) * 65 + sl] = vv[i];
  __syncthreads();
  int d = t >> 1, half = t & 1;
  size_t voff = (size_t)((b * H_ + h) * D_ + d) * S_ + st * 64 + half * 32;
#pragma unroll
  for (int i = 0; i < 4; i++) {
    bf16x8 tv;
#pragma unroll
    for (int j = 0; j < 8; j++) tv[j] = vtile[d * 65 + half * 32 + i * 8 + j];
    *(bf16x8*)(Vt + voff + i * 8) = tv;
  }
}

// ---------------- flash attention: independent waves, uniform work ----------------
// 512 blocks x 4 waves. Wave handles strip pair (p, 127-p): (p/4+1)+((127-p)/4+1)=33
// k-tiles for EVERY wave (perfect balance). Block's 4 waves take adjacent strips
// 4g..4g+3 (identical trip counts -> natural lockstep -> L1 K/V reuse). No barriers:
// the P transpose buffer is per-wave; wave-internal lgkmcnt ordering suffices.
__global__ __launch_bounds__(256) void flash_k(const bf16* __restrict__ Q,
                                               const bf16* __restrict__ K,
                                               const bf16* __restrict__ Vt,
                                               const float* __restrict__ amask,
                                               bf16* __restrict__ O) {
  __shared__ __align__(16) bf16 pbuf[4][1024];
  int blk = blockIdx.x;
  int bh = blk & 31;       // same bh for co-scheduled blocks c, c+256 -> L1/L2 affinity
  int g = blk >> 5;        // 0..15
  int b = bh >> 4, h = bh & 15;
  int t = threadIdx.x;
  int w = t >> 6, l = t & 63;
  int quad = l >> 4, ln = l & 15;
  int p = g * 4 + w;       // 0..63

  const bf16* Kbase = K + (size_t)bh * (S_ * D_);
  const bf16* Vbase = Vt + (size_t)bh * (S_ * D_);
  const float* mbase = amask + (size_t)b * S_;
  bf16* pw = pbuf[w];
  const float scale = 0.08838834764831845f;  // 1/sqrt(128)

#pragma unroll 1
  for (int half = 0; half < 2; half++) {
    int strip = half ? (127 - p) : p;
    int qrow = strip * 16;
    int ktiles = (qrow >> 6) + 1;

    const bf16* Qp = Q + (size_t)(bh * S_ + qrow + ln) * D_;
    bf16x8 qf[4];
#pragma unroll
    for (int ks = 0; ks < 4; ks++)
      qf[ks] = *(const bf16x8*)(Qp + ks * 32 + quad * 8);

    floatx4 o_acc[8] = {};
    float m_i[4] = {-1e30f, -1e30f, -1e30f, -1e30f};
    float l_i[4] = {0.f, 0.f, 0.f, 0.f};

    for (int kt = 0; kt < ktiles; kt++) {
      int kv0 = kt * 64;
      float sv[4][4];
#pragma unroll
      for (int nt = 0; nt < 4; nt++) {
        const bf16* kp = Kbase + (size_t)(kv0 + nt * 16 + ln) * D_ + quad * 8;
        floatx4 acc = {};
#pragma unroll
        for (int ks = 0; ks < 4; ks++)
          acc = MFMA16(qf[ks], *(const bf16x8*)(kp + ks * 32), acc);
        int col = kv0 + nt * 16 + ln;
        float am = mbase[col];
#pragma unroll
        for (int r = 0; r < 4; r++) {
          float v = acc[r] * scale + am;
          if (col > qrow + quad * 4 + r) v = -3.0e38f;  // causal
          sv[nt][r] = v;
        }
      }
#pragma unroll
      for (int r = 0; r < 4; r++) {
        float mx = fmaxf(fmaxf(sv[0][r], sv[1][r]), fmaxf(sv[2][r], sv[3][r]));
#pragma unroll
        for (int off = 1; off < 16; off <<= 1)
          mx = fmaxf(mx, __shfl_xor(mx, off, 64));
        float mnew = fmaxf(m_i[r], mx);
        float sum = 0.f;
#pragma unroll
        for (int nt = 0; nt < 4; nt++) {
          float pe = __expf(sv[nt][r] - mnew);
          sv[nt][r] = pe;
          sum += pe;
        }
#pragma unroll
        for (int off = 1; off < 16; off <<= 1)
          sum += __shfl_xor(sum, off, 64);
        float alpha = __expf(m_i[r] - mnew);
        l_i[r] = l_i[r] * alpha + sum;
        m_i[r] = mnew;
#pragma unroll
        for (int dt = 0; dt < 8; dt++) o_acc[dt][r] *= alpha;
      }
      // P: C-layout -> A-layout through per-wave LDS (no block barrier needed)
#pragma unroll
      for (int nt = 0; nt < 4; nt++)
#pragma unroll
        for (int r = 0; r < 4; r++)
          pw[(quad * 4 + r) * 64 + nt * 16 + ln] = (bf16)sv[nt][r];
      bf16x8 pf0 = *(const bf16x8*)(pw + ln * 64 + quad * 8);
      bf16x8 pf1 = *(const bf16x8*)(pw + ln * 64 + 32 + quad * 8);
#pragma unroll
      for (int dt = 0; dt < 8; dt++) {
        const bf16* vp = Vbase + (size_t)(dt * 16 + ln) * S_ + kv0 + quad * 8;
        floatx4 acc = o_acc[dt];
        acc = MFMA16(pf0, *(const bf16x8*)vp, acc);
        acc = MFMA16(pf1, *(const bf16x8*)(vp + 32), acc);
        o_acc[dt] = acc;
      }
    }

#pragma unroll
    for (int r = 0; r < 4; r++) {
      float inv_l = 1.0f / l_i[r];
      int qq = qrow + quad * 4 + r;
      bf16* op = O + (size_t)(b * S_ + qq) * HID_ + h * D_ + ln;
#pragma unroll
      for (int dt = 0; dt < 8; dt++)
        op[dt * 16] = (bf16)(o_acc[dt][r] * inv_l);
    }
  }
}

// ---------------- launch ----------------
extern "C" void kernel_launch(void* const* d_in, const int* in_sizes, int n_in,
                              void* d_out, int out_size, void* d_ws, size_t ws_size,
                              hipStream_t stream) {
  const float* hidden = (const float*)d_in[0];
  const float* amask = (const float*)d_in[1];
  const float* Wqkv = (const float*)d_in[2];
  const float* Wdense = (const float*)d_in[3];
  const int* posids = (const int*)d_in[4];
  float* out = (float*)d_out;
  char* ws = (char*)d_ws;

  bf16* wdT = (bf16*)(ws + 0);
  bf16* qkv = (bf16*)(ws + 8388608ull);
  bf16* hsb = (bf16*)(ws + 58720256ull);
  bf16* attn = (bf16*)(ws + 58720256ull);
  bf16* wqT = (bf16*)(ws + 75497472ull);
  bf16* Qb = (bf16*)(ws + 75497472ull);
  bf16* Kb = (bf16*)(ws + 92274688ull);
  bf16* Vtb = (bf16*)(ws + 109051904ull);

  cast_bf16_k<<<8192, 256, 0, stream>>>(hidden, hsb);
  transpose_cast_k<<<dim3(96, 32), 256, 0, stream>>>(Wqkv, wqT, 2048, 6144);
  transpose_cast_k<<<dim3(32, 32), 256, 0, stream>>>(Wdense, wdT, 2048, 2048);
  gemm_bt_k<bf16><<<dim3(32, 48), 256, 0, stream>>>(hsb, wqT, qkv, 4096, 6144, 2048);
  qkv_transform_k<<<1024, 256, 0, stream>>>(qkv, posids, Qb, Kb, Vtb);
  flash_k<<<512, 256, 0, stream>>>(Qb, Kb, Vtb, amask, attn);
  gemm_bt_k<float><<<dim3(32, 16), 256, 0, stream>>>(attn, wdT, out, 4096, 2048, 2048);
}

// Round 3
// 600.092 us; speedup vs baseline: 1.4505x; 1.0038x over previous
//
#include <hip/hip_runtime.h>
#include <stdint.h>

#define B_ 2
#define S_ 2048
#define HID_ 2048
#define H_ 16
#define D_ 128
#define LOG2E 1.44269504088896f

typedef __bf16 bf16;
typedef __bf16 bf16x8 __attribute__((ext_vector_type(8)));
typedef __bf16 bf16x4 __attribute__((ext_vector_type(4)));
typedef float floatx4 __attribute__((ext_vector_type(4)));

#define MFMA16(a, b, c) __builtin_amdgcn_mfma_f32_16x16x32_bf16(a, b, c, 0, 0, 0)

__device__ __forceinline__ void gload_lds16(const bf16* g, bf16* l) {
  __builtin_amdgcn_global_load_lds(
      (const __attribute__((address_space(1))) uint32_t*)g,
      (__attribute__((address_space(3))) uint32_t*)l, 16, 0, 0);
}

// ---------------- cast fp32 -> bf16 (flat) ----------------
__global__ __launch_bounds__(256) void cast_bf16_k(const float* __restrict__ in,
                                                   bf16* __restrict__ out) {
  size_t i = ((size_t)blockIdx.x * 256 + threadIdx.x) * 4;
  float4 v = *(const float4*)(in + i);
  bf16x4 o;
  o[0] = (bf16)v.x; o[1] = (bf16)v.y; o[2] = (bf16)v.z; o[3] = (bf16)v.w;
  *(bf16x4*)(out + i) = o;
}

// ---------------- transpose + cast: in (R x C) f32 -> out (C x R) bf16 ----------------
__global__ __launch_bounds__(256) void transpose_cast_k(const float* __restrict__ in,
                                                        bf16* __restrict__ out,
                                                        int R, int C) {
  __shared__ bf16 tile[64][65];
  int tc = blockIdx.x * 64, tr = blockIdx.y * 64;
  int t = threadIdx.x;
  int c = t & 63, r0 = t >> 6;
  const float* ip = in + (size_t)(tr + r0) * C + tc + c;
#pragma unroll
  for (int i = 0; i < 16; i++)
    tile[r0 + i * 4][c] = (bf16)ip[(size_t)i * 4 * C];
  __syncthreads();
  int n = t >> 2, ch = t & 3;
  bf16x8 v0, v1;
#pragma unroll
  for (int j = 0; j < 8; j++) {
    v0[j] = tile[ch * 16 + j][n];
    v1[j] = tile[ch * 16 + 8 + j][n];
  }
  bf16* op = out + (size_t)(tc + n) * R + tr + ch * 16;
  *(bf16x8*)op = v0;
  *(bf16x8*)(op + 8) = v1;
}

// ---------------- GEMM: C[M,N] = A[M,K] * Bt[N,K]^T   (m97 structure) ----------------
template <typename OutT>
__global__ __launch_bounds__(256) void gemm_bt_k(const bf16* __restrict__ A,
                                                 const bf16* __restrict__ Bt,
                                                 OutT* __restrict__ C,
                                                 int M, int N, int K) {
  __shared__ __align__(16) bf16 As[4096];
  __shared__ __align__(16) bf16 Bs[4096];
  const int t = threadIdx.x;
  const int w = t >> 6, l = t & 63;
  const int quad = l >> 4, ln = l & 15;
  const int wm = w >> 1, wn = w & 1;
  const int m0 = blockIdx.x * 128, n0 = blockIdx.y * 128;

  floatx4 acc[4][4] = {};

  const int srow = w * 32 + (l >> 2);
  const int skoff = (l & 3) * 8;
  const bf16* Ag = A + (size_t)(m0 + srow) * K + skoff;
  const bf16* Bg = Bt + (size_t)(n0 + srow) * K + skoff;
  bf16* AsW0 = As + (2 * w + 0) * 512;
  bf16* AsW1 = As + (2 * w + 1) * 512;
  bf16* BsW0 = Bs + (2 * w + 0) * 512;
  bf16* BsW1 = Bs + (2 * w + 1) * 512;
  const size_t rstep = (size_t)16 * K;

  for (int kt = 0; kt < K; kt += 32) {
    gload_lds16(Ag + kt, AsW0);
    gload_lds16(Ag + kt + rstep, AsW1);
    gload_lds16(Bg + kt, BsW0);
    gload_lds16(Bg + kt + rstep, BsW1);
    __syncthreads();
    bf16x8 af[4], bfr[4];
#pragma unroll
    for (int mt = 0; mt < 4; mt++)
      af[mt] = *(const bf16x8*)(As + (wm * 64 + mt * 16 + ln) * 32 + quad * 8);
#pragma unroll
    for (int nt = 0; nt < 4; nt++)
      bfr[nt] = *(const bf16x8*)(Bs + (wn * 64 + nt * 16 + ln) * 32 + quad * 8);
#pragma unroll
    for (int mt = 0; mt < 4; mt++)
#pragma unroll
      for (int nt = 0; nt < 4; nt++)
        acc[mt][nt] = MFMA16(af[mt], bfr[nt], acc[mt][nt]);
    __syncthreads();
  }

#pragma unroll
  for (int mt = 0; mt < 4; mt++)
#pragma unroll
    for (int nt = 0; nt < 4; nt++) {
      int row = m0 + wm * 64 + mt * 16 + quad * 4;
      int col = n0 + wn * 64 + nt * 16 + ln;
      OutT* cp = C + (size_t)row * N + col;
#pragma unroll
      for (int r = 0; r < 4; r++)
        cp[(size_t)r * N] = (OutT)acc[mt][nt][r];
    }
}

// ---------------- qkv split + xPos rotary (+ Q pre-scale) + V transpose ----------------
__global__ __launch_bounds__(256) void qkv_transform_k(const bf16* __restrict__ qkv,
                                                       const int* __restrict__ pos_ids,
                                                       bf16* __restrict__ Q,
                                                       bf16* __restrict__ Kk,
                                                       bf16* __restrict__ Vt) {
  __shared__ bf16 vtile[128 * 65];
  const float QS = 0.08838834764831845f * LOG2E;  // 1/sqrt(128) * log2(e)
  int blk = blockIdx.x;
  int st = blk & 31;
  int h = (blk >> 5) & 15;
  int b = blk >> 9;
  int t = threadIdx.x;
  int sl = t >> 2, dg = t & 3;
  int s = st * 64 + sl;
  float tp = (float)pos_ids[b * S_ + s];

  const bf16* base = qkv + (size_t)(b * S_ + s) * (3 * HID_) + h * (3 * D_) + dg * 32;
  bf16 qv[32], kv[32], vv[32];
#pragma unroll
  for (int i = 0; i < 4; i++) ((bf16x8*)qv)[i] = *(const bf16x8*)(base + i * 8);
#pragma unroll
  for (int i = 0; i < 4; i++) ((bf16x8*)kv)[i] = *(const bf16x8*)(base + D_ + i * 8);
#pragma unroll
  for (int i = 0; i < 4; i++) ((bf16x8*)vv)[i] = *(const bf16x8*)(base + 2 * D_ + i * 8);

  if (dg == 0) {  // rotary covers dims 0..31 exactly
    float power = (tp - 1024.0f) * (1.0f / 512.0f);
#pragma unroll
    for (int i = 0; i < 16; i++) {
      float inv_freq = powf(10000.0f, -(float)i * (1.0f / 16.0f));
      float fr = tp * inv_freq;
      float cs = cosf(fr), sn = sinf(fr);
      float scl = ((float)(2 * i) + 12.8f) * (1.0f / 44.8f);
      float sc = powf(scl, power);
      float cq = cs * sc, sq = sn * sc;
      float ck = cs / sc, sk = sn / sc;
      float q1 = (float)qv[i], q2 = (float)qv[i + 16];
      float k1 = (float)kv[i], k2 = (float)kv[i + 16];
      qv[i] = (bf16)(q1 * cq - q2 * sq);
      qv[i + 16] = (bf16)(q2 * cq + q1 * sq);
      kv[i] = (bf16)(k1 * ck - k2 * sk);
      kv[i + 16] = (bf16)(k2 * ck + k1 * sk);
    }
  }
  // pre-scale Q by 1/sqrt(D) * log2(e) (softmax done in exp2 domain)
#pragma unroll
  for (int i = 0; i < 32; i++) qv[i] = (bf16)((float)qv[i] * QS);

  size_t qoff = (size_t)((b * H_ + h) * S_ + s) * D_ + dg * 32;
#pragma unroll
  for (int i = 0; i < 4; i++) *(bf16x8*)(Q + qoff + i * 8) = ((bf16x8*)qv)[i];
#pragma unroll
  for (int i = 0; i < 4; i++) *(bf16x8*)(Kk + qoff + i * 8) = ((bf16x8*)kv)[i];

#pragma unroll
  for (int i = 0; i < 32; i++) vtile[(dg * 32 + i) * 65 + sl] = vv[i];
  __syncthreads();
  int d = t >> 1, half = t & 1;
  size_t voff = (size_t)((b * H_ + h) * D_ + d) * S_ + st * 64 + half * 32;
#pragma unroll
  for (int i = 0; i < 4; i++) {
    bf16x8 tv;
#pragma unroll
    for (int j = 0; j < 8; j++) tv[j] = vtile[d * 65 + half * 32 + i * 8 + j];
    *(bf16x8*)(Vt + voff + i * 8) = tv;
  }
}

// ---------------- flash attention, S^T formulation + 2-way split-K ----------------
// Grid: 1024 blocks = 32 bh x 32 job-pairs (jp ascending = longest first).
// Block: 4 waves. Jobs A=63-2jp, B=62-2jp (both 32 q-rows, equal k-trips T=32-jp).
// Waves: w0=A-lo, w1=A-hi, w2=B-lo, w3=B-hi (k-range split [0,T/2) / [T/2,T)).
// QK^T computed transposed (A=K-frag, B=Q-frag -> C=S^T): softmax rows are lane
// columns (2 shfls per reduction); P^T written as packed b64 to pad-72 LDS; PV
// computed as V^T * P^T -> O^T. Hi waves dump O^T/m/l to LDS; lo waves merge.
__global__ __launch_bounds__(256, 3) void flash_k(const bf16* __restrict__ Q,
                                                  const bf16* __restrict__ K,
                                                  const bf16* __restrict__ Vt,
                                                  const float* __restrict__ amask,
                                                  bf16* __restrict__ O) {
  __shared__ __align__(16) char ldsraw[32768];  // union: pbuf (4x4608B) | obuf (2x16KB)
  __shared__ float mlb[2][4][64];
  bf16* pbase = (bf16*)ldsraw;
  float* obuf = (float*)ldsraw;

  int blk = blockIdx.x;
  int bh = blk & 31;
  int jp = blk >> 5;  // 0..31, ascending -> longest jobs dispatched first
  int b = bh >> 4, h = bh & 15;
  int t = threadIdx.x;
  int w = t >> 6, l = t & 63;
  int quad = l >> 4, ln = l & 15;
  int pair = w >> 1, half = w & 1;
  int job = (pair ? 62 : 63) - 2 * jp;
  int qs = job * 32;
  int T = (job >> 1) + 1;
  int Tlo = T >> 1;
  int kt0 = half ? Tlo : 0;
  int kt1 = half ? T : Tlo;

  const bf16* Kbase = K + (size_t)bh * (S_ * D_);
  const bf16* Vbase = Vt + (size_t)bh * (S_ * D_);
  const float* mbase = amask + (size_t)b * S_;
  bf16* pw = pbase + w * (32 * 72);

  // Q B-fragments (persistent; Q pre-scaled by 1/sqrt(D)*log2e)
  bf16x8 qf[2][4];
#pragma unroll
  for (int nt = 0; nt < 2; nt++)
#pragma unroll
    for (int ks = 0; ks < 4; ks++)
      qf[nt][ks] = *(const bf16x8*)(Q + (size_t)(bh * S_ + qs + nt * 16 + ln) * D_ +
                                    ks * 32 + quad * 8);

  floatx4 oacc[8][2] = {};
  float m_i[2] = {-1e30f, -1e30f};
  float l_i[2] = {0.f, 0.f};

  for (int kt = kt0; kt < kt1; kt++) {
    int kv0 = kt * 64;
    // ---- S^T = K * Q^T ----
    floatx4 acc[4][2] = {};
#pragma unroll
    for (int ks = 0; ks < 4; ks++) {
      bf16x8 kf[4];
#pragma unroll
      for (int mt = 0; mt < 4; mt++)
        kf[mt] = *(const bf16x8*)(Kbase + (size_t)(kv0 + mt * 16 + ln) * D_ +
                                  ks * 32 + quad * 8);
#pragma unroll
      for (int mt = 0; mt < 4; mt++)
#pragma unroll
        for (int nt = 0; nt < 2; nt++)
          acc[mt][nt] = MFMA16(kf[mt], qf[nt][ks], acc[mt][nt]);
    }
    floatx4 am[4];
#pragma unroll
    for (int mt = 0; mt < 4; mt++)
      am[mt] = *(const floatx4*)(mbase + kv0 + mt * 16 + quad * 4);

    bool diag = (kt == T - 1);  // only the last global tile crosses the diagonal
    // ---- online softmax (rows = lane columns) + P^T write ----
#pragma unroll
    for (int nt = 0; nt < 2; nt++) {
      int q = qs + nt * 16 + ln;
      float v[4][4];
#pragma unroll
      for (int mt = 0; mt < 4; mt++)
#pragma unroll
        for (int r = 0; r < 4; r++) {
          float x = acc[mt][nt][r] + am[mt][r] * LOG2E;
          if (diag && (kv0 + mt * 16 + quad * 4 + r > q)) x = -3.0e38f;
          v[mt][r] = x;
        }
      float mx = v[0][0];
#pragma unroll
      for (int mt = 0; mt < 4; mt++)
#pragma unroll
        for (int r = 0; r < 4; r++) mx = fmaxf(mx, v[mt][r]);
      mx = fmaxf(mx, __shfl_xor(mx, 16, 64));
      mx = fmaxf(mx, __shfl_xor(mx, 32, 64));
      float mnew = fmaxf(m_i[nt], mx);
      float sum = 0.f;
      bf16x4 pk[4];
#pragma unroll
      for (int mt = 0; mt < 4; mt++)
#pragma unroll
        for (int r = 0; r < 4; r++) {
          float p = exp2f(v[mt][r] - mnew);
          sum += p;
          pk[mt][r] = (bf16)p;
        }
      sum += __shfl_xor(sum, 16, 64);
      sum += __shfl_xor(sum, 32, 64);
      float alpha = exp2f(m_i[nt] - mnew);
      l_i[nt] = l_i[nt] * alpha + sum;
      m_i[nt] = mnew;
#pragma unroll
      for (int dt = 0; dt < 8; dt++) oacc[dt][nt] *= alpha;
#pragma unroll
      for (int mt = 0; mt < 4; mt++)
        *(bf16x4*)(pw + (nt * 16 + ln) * 72 + mt * 16 + quad * 4) = pk[mt];
    }
    // ---- O^T += V^T * P^T ----
#pragma unroll
    for (int ks = 0; ks < 2; ks++) {
      bf16x8 pf[2];
#pragma unroll
      for (int nt = 0; nt < 2; nt++)
        pf[nt] = *(const bf16x8*)(pw + (nt * 16 + ln) * 72 + ks * 32 + quad * 8);
#pragma unroll
      for (int dt = 0; dt < 8; dt++) {
        bf16x8 vf = *(const bf16x8*)(Vbase + (size_t)(dt * 16 + ln) * S_ +
                                     kv0 + ks * 32 + quad * 8);
#pragma unroll
        for (int nt = 0; nt < 2; nt++)
          oacc[dt][nt] = MFMA16(vf, pf[nt], oacc[dt][nt]);
      }
    }
  }

  // ---- split-K merge through LDS ----
  __syncthreads();  // all loops done; pbuf region free for obuf reuse
  if (half) {
    float* ob = obuf + pair * 4096;
#pragma unroll
    for (int dt = 0; dt < 8; dt++)
#pragma unroll
      for (int nt = 0; nt < 2; nt++)
#pragma unroll
        for (int r = 0; r < 4; r++)
          ob[(dt * 8 + nt * 4 + r) * 64 + l] = oacc[dt][nt][r];
    mlb[pair][0][l] = m_i[0];
    mlb[pair][1][l] = l_i[0];
    mlb[pair][2][l] = m_i[1];
    mlb[pair][3][l] = l_i[1];
  }
  __syncthreads();
  if (!half) {
    float aA[2], aB[2], inv[2];
#pragma unroll
    for (int nt = 0; nt < 2; nt++) {
      float mB = mlb[pair][nt * 2][l];
      float lB = mlb[pair][nt * 2 + 1][l];
      float mS = fmaxf(m_i[nt], mB);
      aA[nt] = exp2f(m_i[nt] - mS);
      aB[nt] = exp2f(mB - mS);
      float lS = l_i[nt] * aA[nt] + lB * aB[nt];
      inv[nt] = 1.0f / lS;
    }
    float* ob = obuf + pair * 4096;
#pragma unroll
    for (int dt = 0; dt < 8; dt++)
#pragma unroll
      for (int nt = 0; nt < 2; nt++) {
        bf16x4 ov;
#pragma unroll
        for (int r = 0; r < 4; r++) {
          float oB = ob[(dt * 8 + nt * 4 + r) * 64 + l];
          ov[r] = (bf16)((oacc[dt][nt][r] * aA[nt] + oB * aB[nt]) * inv[nt]);
        }
        *(bf16x4*)(O + (size_t)(b * S_ + qs + nt * 16 + ln) * HID_ +
                   h * D_ + dt * 16 + quad * 4) = ov;
      }
  }
}

// ---------------- launch ----------------
extern "C" void kernel_launch(void* const* d_in, const int* in_sizes, int n_in,
                              void* d_out, int out_size, void* d_ws, size_t ws_size,
                              hipStream_t stream) {
  const float* hidden = (const float*)d_in[0];
  const float* amask = (const float*)d_in[1];
  const float* Wqkv = (const float*)d_in[2];
  const float* Wdense = (const float*)d_in[3];
  const int* posids = (const int*)d_in[4];
  float* out = (float*)d_out;
  char* ws = (char*)d_ws;

  bf16* wdT = (bf16*)(ws + 0);
  bf16* qkv = (bf16*)(ws + 8388608ull);
  bf16* hsb = (bf16*)(ws + 58720256ull);
  bf16* attn = (bf16*)(ws + 58720256ull);
  bf16* wqT = (bf16*)(ws + 75497472ull);
  bf16* Qb = (bf16*)(ws + 75497472ull);
  bf16* Kb = (bf16*)(ws + 92274688ull);
  bf16* Vtb = (bf16*)(ws + 109051904ull);

  cast_bf16_k<<<8192, 256, 0, stream>>>(hidden, hsb);
  transpose_cast_k<<<dim3(96, 32), 256, 0, stream>>>(Wqkv, wqT, 2048, 6144);
  transpose_cast_k<<<dim3(32, 32), 256, 0, stream>>>(Wdense, wdT, 2048, 2048);
  gemm_bt_k<bf16><<<dim3(32, 48), 256, 0, stream>>>(hsb, wqT, qkv, 4096, 6144, 2048);
  qkv_transform_k<<<1024, 256, 0, stream>>>(qkv, posids, Qb, Kb, Vtb);
  flash_k<<<1024, 256, 0, stream>>>(Qb, Kb, Vtb, amask, attn);
  gemm_bt_k<float><<<dim3(32, 16), 256, 0, stream>>>(attn, wdT, out, 4096, 2048, 2048);
}

// Round 4
// 438.604 us; speedup vs baseline: 1.9845x; 1.3682x over previous
//
#include <hip/hip_runtime.h>
#include <stdint.h>

#define B_ 2
#define S_ 2048
#define HID_ 2048
#define H_ 16
#define D_ 128
#define LOG2E 1.44269504088896f

typedef __bf16 bf16;
typedef __bf16 bf16x8 __attribute__((ext_vector_type(8)));
typedef __bf16 bf16x4 __attribute__((ext_vector_type(4)));
typedef float floatx4 __attribute__((ext_vector_type(4)));

#define MFMA16(a, b, c) __builtin_amdgcn_mfma_f32_16x16x32_bf16(a, b, c, 0, 0, 0)

__device__ __forceinline__ void gload_lds16(const bf16* g, bf16* l) {
  __builtin_amdgcn_global_load_lds(
      (const __attribute__((address_space(1))) uint32_t*)g,
      (__attribute__((address_space(3))) uint32_t*)l, 16, 0, 0);
}

// ---------------- cast fp32 -> bf16 (flat) ----------------
__global__ __launch_bounds__(256) void cast_bf16_k(const float* __restrict__ in,
                                                   bf16* __restrict__ out) {
  size_t i = ((size_t)blockIdx.x * 256 + threadIdx.x) * 4;
  float4 v = *(const float4*)(in + i);
  bf16x4 o;
  o[0] = (bf16)v.x; o[1] = (bf16)v.y; o[2] = (bf16)v.z; o[3] = (bf16)v.w;
  *(bf16x4*)(out + i) = o;
}

// ---------------- transpose + cast: in (R x C) f32 -> out (C x R) bf16 ----------------
__global__ __launch_bounds__(256) void transpose_cast_k(const float* __restrict__ in,
                                                        bf16* __restrict__ out,
                                                        int R, int C) {
  __shared__ bf16 tile[64][65];
  int tc = blockIdx.x * 64, tr = blockIdx.y * 64;
  int t = threadIdx.x;
  int c = t & 63, r0 = t >> 6;
  const float* ip = in + (size_t)(tr + r0) * C + tc + c;
#pragma unroll
  for (int i = 0; i < 16; i++)
    tile[r0 + i * 4][c] = (bf16)ip[(size_t)i * 4 * C];
  __syncthreads();
  int n = t >> 2, ch = t & 3;
  bf16x8 v0, v1;
#pragma unroll
  for (int j = 0; j < 8; j++) {
    v0[j] = tile[ch * 16 + j][n];
    v1[j] = tile[ch * 16 + 8 + j][n];
  }
  bf16* op = out + (size_t)(tc + n) * R + tr + ch * 16;
  *(bf16x8*)op = v0;
  *(bf16x8*)(op + 8) = v1;
}

// ---------------- GEMM: C[M,N] = A[M,K] * Bt[N,K]^T   (m97 structure) ----------------
template <typename OutT>
__global__ __launch_bounds__(256) void gemm_bt_k(const bf16* __restrict__ A,
                                                 const bf16* __restrict__ Bt,
                                                 OutT* __restrict__ C,
                                                 int M, int N, int K) {
  __shared__ __align__(16) bf16 As[4096];
  __shared__ __align__(16) bf16 Bs[4096];
  const int t = threadIdx.x;
  const int w = t >> 6, l = t & 63;
  const int quad = l >> 4, ln = l & 15;
  const int wm = w >> 1, wn = w & 1;
  const int m0 = blockIdx.x * 128, n0 = blockIdx.y * 128;

  floatx4 acc[4][4] = {};

  const int srow = w * 32 + (l >> 2);
  const int skoff = (l & 3) * 8;
  const bf16* Ag = A + (size_t)(m0 + srow) * K + skoff;
  const bf16* Bg = Bt + (size_t)(n0 + srow) * K + skoff;
  bf16* AsW0 = As + (2 * w + 0) * 512;
  bf16* AsW1 = As + (2 * w + 1) * 512;
  bf16* BsW0 = Bs + (2 * w + 0) * 512;
  bf16* BsW1 = Bs + (2 * w + 1) * 512;
  const size_t rstep = (size_t)16 * K;

  for (int kt = 0; kt < K; kt += 32) {
    gload_lds16(Ag + kt, AsW0);
    gload_lds16(Ag + kt + rstep, AsW1);
    gload_lds16(Bg + kt, BsW0);
    gload_lds16(Bg + kt + rstep, BsW1);
    __syncthreads();
    bf16x8 af[4], bfr[4];
#pragma unroll
    for (int mt = 0; mt < 4; mt++)
      af[mt] = *(const bf16x8*)(As + (wm * 64 + mt * 16 + ln) * 32 + quad * 8);
#pragma unroll
    for (int nt = 0; nt < 4; nt++)
      bfr[nt] = *(const bf16x8*)(Bs + (wn * 64 + nt * 16 + ln) * 32 + quad * 8);
#pragma unroll
    for (int mt = 0; mt < 4; mt++)
#pragma unroll
      for (int nt = 0; nt < 4; nt++)
        acc[mt][nt] = MFMA16(af[mt], bfr[nt], acc[mt][nt]);
    __syncthreads();
  }

#pragma unroll
  for (int mt = 0; mt < 4; mt++)
#pragma unroll
    for (int nt = 0; nt < 4; nt++) {
      int row = m0 + wm * 64 + mt * 16 + quad * 4;
      int col = n0 + wn * 64 + nt * 16 + ln;
      OutT* cp = C + (size_t)row * N + col;
#pragma unroll
      for (int r = 0; r < 4; r++)
        cp[(size_t)r * N] = (OutT)acc[mt][nt][r];
    }
}

// ---------------- qkv split + xPos rotary + packed K/V layouts ----------------
// Kp[bh][kvblk(32)][chunk(16)=mt*4+ks][lane(64)][8 elems]:
//   chunk bytes for lane l = K[kv0+mt*16+(l&15)][ks*32+(l>>4)*8 .. +8]
// Vp[bh][kvblk(32)][chunk(16)=dt*2+ks][lane(64)][8 elems]:
//   chunk bytes for lane l = V[kv0+ks*32+(l>>4)*8+j][dt*16+(l&15)], j=0..7
// A linear 16B-per-lane DMA of a chunk then yields lane-linear LDS fragments.
__global__ __launch_bounds__(256) void qkv_transform_k(const bf16* __restrict__ qkv,
                                                       const int* __restrict__ pos_ids,
                                                       bf16* __restrict__ Q,
                                                       bf16* __restrict__ Kp,
                                                       bf16* __restrict__ Vp) {
  __shared__ __align__(16) bf16 vtile[128 * 72];
  const float QS = 0.08838834764831845f * LOG2E;  // 1/sqrt(128) * log2(e)
  int blk = blockIdx.x;
  int st = blk & 31;            // kvblk
  int h = (blk >> 5) & 15;
  int b = blk >> 9;
  int bh = b * H_ + h;
  int t = threadIdx.x;
  int sl = t >> 2, dg = t & 3;
  int s = st * 64 + sl;
  float tp = (float)pos_ids[b * S_ + s];

  const bf16* base = qkv + (size_t)(b * S_ + s) * (3 * HID_) + h * (3 * D_) + dg * 32;
  bf16 qv[32], kv[32], vv[32];
#pragma unroll
  for (int i = 0; i < 4; i++) ((bf16x8*)qv)[i] = *(const bf16x8*)(base + i * 8);
#pragma unroll
  for (int i = 0; i < 4; i++) ((bf16x8*)kv)[i] = *(const bf16x8*)(base + D_ + i * 8);
#pragma unroll
  for (int i = 0; i < 4; i++) ((bf16x8*)vv)[i] = *(const bf16x8*)(base + 2 * D_ + i * 8);

  if (dg == 0) {  // rotary covers dims 0..31 exactly
    float power = (tp - 1024.0f) * (1.0f / 512.0f);
#pragma unroll
    for (int i = 0; i < 16; i++) {
      float inv_freq = powf(10000.0f, -(float)i * (1.0f / 16.0f));
      float fr = tp * inv_freq;
      float cs = cosf(fr), sn = sinf(fr);
      float scl = ((float)(2 * i) + 12.8f) * (1.0f / 44.8f);
      float sc = powf(scl, power);
      float cq = cs * sc, sq = sn * sc;
      float ck = cs / sc, sk = sn / sc;
      float q1 = (float)qv[i], q2 = (float)qv[i + 16];
      float k1 = (float)kv[i], k2 = (float)kv[i + 16];
      qv[i] = (bf16)(q1 * cq - q2 * sq);
      qv[i + 16] = (bf16)(q2 * cq + q1 * sq);
      kv[i] = (bf16)(k1 * ck - k2 * sk);
      kv[i + 16] = (bf16)(k2 * ck + k1 * sk);
    }
  }
  // pre-scale Q by 1/sqrt(D) * log2(e) (softmax done in exp2 domain)
#pragma unroll
  for (int i = 0; i < 32; i++) qv[i] = (bf16)((float)qv[i] * QS);

  size_t qoff = (size_t)(bh * S_ + s) * D_ + dg * 32;
#pragma unroll
  for (int i = 0; i < 4; i++) *(bf16x8*)(Q + qoff + i * 8) = ((bf16x8*)qv)[i];

  // Kp packed store: thread (sl,dg) holds rows sl, d in [dg*32, dg*32+32)
  {
    int mt = sl >> 4, lnq = sl & 15;
    bf16* kdst = Kp + (size_t)bh * (S_ * D_) + (size_t)st * 8192 + (mt * 4 + dg) * 512;
#pragma unroll
    for (int q = 0; q < 4; q++)
      *(bf16x8*)(kdst + (q * 16 + lnq) * 8) = ((bf16x8*)kv)[q];
  }

  // V -> vtile[d][s_local] (stride 72, 16B-aligned rows)
#pragma unroll
  for (int i = 0; i < 32; i++) vtile[(dg * 32 + i) * 72 + sl] = vv[i];
  __syncthreads();

  // Vp packed store
  {
    int c = t >> 4, sub = t & 15;
    int dt = c >> 1, ksv = c & 1;
    bf16* vdst = Vp + (size_t)bh * (S_ * D_) + (size_t)st * 8192 + c * 512;
#pragma unroll
    for (int li = 0; li < 4; li++) {
      int lf = sub * 4 + li;
      int lq = lf >> 4, lln = lf & 15;
      bf16x8 tv = *(const bf16x8*)(vtile + (dt * 16 + lln) * 72 + ksv * 32 + lq * 8);
      *(bf16x8*)(vdst + lf * 8) = tv;
    }
  }
}

// ---------------- flash attention: lockstep waves + double-buffered LDS DMA ----------------
// Grid 512 = 32 bh x 16 ab. Block phase0: strips {4*ab..4*ab+3} (T=ab+1 tiles);
// phase1: strips {4*(31-ab)..} (T=32-ab). Every wave: exactly 33 barrier-synced tiles.
// Per tile: 32KB K/V staged by all 4 waves via global_load_lds into the next buffer
// (issued right after the barrier -> full tile of compute covers the latency), then
// consumed as lane-linear conflict-free ds_read_b128 fragments (Kp/Vp pre-swizzle).
__global__ __launch_bounds__(256, 2) void flash_k(const bf16* __restrict__ Q,
                                                  const bf16* __restrict__ Kp,
                                                  const bf16* __restrict__ Vp,
                                                  const float* __restrict__ amask,
                                                  bf16* __restrict__ O) {
  __shared__ __align__(16) bf16 stage[2][16384];  // [0,8192)=K chunks, [8192,16384)=V chunks
  __shared__ __align__(16) bf16 pbuf[4][16 * 72];
  int blk = blockIdx.x;
  int bh = blk & 31;
  int ab = blk >> 5;  // 0..15
  int b = bh >> 4, h = bh & 15;
  int t = threadIdx.x;
  int w = t >> 6, l = t & 63;
  int quad = l >> 4, ln = l & 15;

  const bf16* Kpb = Kp + (size_t)bh * (S_ * D_);
  const bf16* Vpb = Vp + (size_t)bh * (S_ * D_);
  const float* mbase = amask + (size_t)b * S_;
  bf16* pw = pbuf[w];

  // prologue: stage tile kvblk 0 into buf 0 (wave w stages chunks w*8..w*8+7 of 32)
#pragma unroll
  for (int j = 0; j < 8; j++) {
    int gi = w * 8 + j;
    const bf16* src = (gi < 16 ? Kpb + gi * 512 : Vpb + (gi - 16) * 512) + l * 8;
    gload_lds16(src, stage[0] + gi * 512);
  }

  int it = 0;  // global tile counter (0..32) -> buffer parity
#pragma unroll 1
  for (int phase = 0; phase < 2; phase++) {
    int a = phase ? (31 - ab) : ab;
    int strip = a * 4 + w;
    int qs = strip * 16;
    int T = a + 1;

    const bf16* Qp = Q + (size_t)(bh * S_ + qs + ln) * D_;
    bf16x8 qf[4];
#pragma unroll
    for (int ks = 0; ks < 4; ks++)
      qf[ks] = *(const bf16x8*)(Qp + ks * 32 + quad * 8);

    floatx4 oacc[8] = {};
    float m_i = -1e30f, l_i = 0.f;

#pragma unroll 1
    for (int kt = 0; kt < T; kt++, it++) {
      __syncthreads();  // own DMA (vmcnt) + all waves' DMA/reads settled
      const bf16* cur = stage[it & 1];
      // issue DMA for the next tile into the other buffer (covered by this tile's compute)
      if (it != 32) {
        int nkv = (kt + 1 < T) ? (kt + 1) : 0;  // next phase starts at kvblk 0
        bf16* nb = stage[(it + 1) & 1];
#pragma unroll
        for (int j = 0; j < 8; j++) {
          int gi = w * 8 + j;
          const bf16* src = (gi < 16 ? Kpb + (size_t)nkv * 8192 + gi * 512
                                     : Vpb + (size_t)nkv * 8192 + (gi - 16) * 512) + l * 8;
          gload_lds16(src, nb + gi * 512);
        }
      }
      int kv0 = kt * 64;

      // ---- S^T = K * Q^T (16 MFMA, fragments lane-linear in LDS) ----
      floatx4 acc[4] = {};
#pragma unroll
      for (int ks = 0; ks < 4; ks++)
#pragma unroll
        for (int mt = 0; mt < 4; mt++) {
          bf16x8 kf = *(const bf16x8*)(cur + (mt * 4 + ks) * 512 + l * 8);
          acc[mt] = MFMA16(kf, qf[ks], acc[mt]);
        }

      floatx4 am4[4];
#pragma unroll
      for (int mt = 0; mt < 4; mt++)
        am4[mt] = *(const floatx4*)(mbase + kv0 + mt * 16 + quad * 4);

      bool diag = (kt == T - 1);
      int q = qs + ln;
      float v[4][4];
      float mx = -3.0e38f;
#pragma unroll
      for (int mt = 0; mt < 4; mt++)
#pragma unroll
        for (int r = 0; r < 4; r++) {
          float x = acc[mt][r] + am4[mt][r] * LOG2E;
          if (diag && (kv0 + mt * 16 + quad * 4 + r > q)) x = -3.0e38f;
          v[mt][r] = x;
          mx = fmaxf(mx, x);
        }
      mx = fmaxf(mx, __shfl_xor(mx, 16, 64));
      mx = fmaxf(mx, __shfl_xor(mx, 32, 64));
      float mnew = fmaxf(m_i, mx);
      float sum = 0.f;
      bf16x4 pk[4];
#pragma unroll
      for (int mt = 0; mt < 4; mt++)
#pragma unroll
        for (int r = 0; r < 4; r++) {
          float p = exp2f(v[mt][r] - mnew);
          sum += p;
          pk[mt][r] = (bf16)p;
        }
      sum += __shfl_xor(sum, 16, 64);
      sum += __shfl_xor(sum, 32, 64);
      float alpha = exp2f(m_i - mnew);
      l_i = l_i * alpha + sum;
      m_i = mnew;
#pragma unroll
      for (int dt = 0; dt < 8; dt++) oacc[dt] *= alpha;

      // P^T via per-wave pad-72 LDS
#pragma unroll
      for (int mt = 0; mt < 4; mt++)
        *(bf16x4*)(pw + ln * 72 + mt * 16 + quad * 4) = pk[mt];

      // ---- O^T += V^T * P^T (16 MFMA) ----
      const bf16* vcur = cur + 8192;
#pragma unroll
      for (int ks = 0; ks < 2; ks++) {
        bf16x8 pf = *(const bf16x8*)(pw + ln * 72 + ks * 32 + quad * 8);
#pragma unroll
        for (int dt = 0; dt < 8; dt++) {
          bf16x8 vf = *(const bf16x8*)(vcur + (dt * 2 + ks) * 512 + l * 8);
          oacc[dt] = MFMA16(vf, pf, oacc[dt]);
        }
      }
    }

    // epilogue: normalize + store O^T (col=q=ln, row=d=dt*16+quad*4+r)
    float inv_l = 1.0f / l_i;
    bf16* op = O + (size_t)(b * S_ + qs + ln) * HID_ + h * D_;
#pragma unroll
    for (int dt = 0; dt < 8; dt++) {
      bf16x4 ov;
#pragma unroll
      for (int r = 0; r < 4; r++) ov[r] = (bf16)(oacc[dt][r] * inv_l);
      *(bf16x4*)(op + dt * 16 + quad * 4) = ov;
    }
  }
}

// ---------------- launch ----------------
extern "C" void kernel_launch(void* const* d_in, const int* in_sizes, int n_in,
                              void* d_out, int out_size, void* d_ws, size_t ws_size,
                              hipStream_t stream) {
  const float* hidden = (const float*)d_in[0];
  const float* amask = (const float*)d_in[1];
  const float* Wqkv = (const float*)d_in[2];
  const float* Wdense = (const float*)d_in[3];
  const int* posids = (const int*)d_in[4];
  float* out = (float*)d_out;
  char* ws = (char*)d_ws;

  bf16* wdT = (bf16*)(ws + 0);
  bf16* qkv = (bf16*)(ws + 8388608ull);
  bf16* hsb = (bf16*)(ws + 58720256ull);
  bf16* attn = (bf16*)(ws + 58720256ull);
  bf16* wqT = (bf16*)(ws + 75497472ull);
  bf16* Qb = (bf16*)(ws + 75497472ull);
  bf16* Kpb = (bf16*)(ws + 92274688ull);
  bf16* Vpb = (bf16*)(ws + 109051904ull);

  cast_bf16_k<<<8192, 256, 0, stream>>>(hidden, hsb);
  transpose_cast_k<<<dim3(96, 32), 256, 0, stream>>>(Wqkv, wqT, 2048, 6144);
  transpose_cast_k<<<dim3(32, 32), 256, 0, stream>>>(Wdense, wdT, 2048, 2048);
  gemm_bt_k<bf16><<<dim3(32, 48), 256, 0, stream>>>(hsb, wqT, qkv, 4096, 6144, 2048);
  qkv_transform_k<<<1024, 256, 0, stream>>>(qkv, posids, Qb, Kpb, Vpb);
  flash_k<<<512, 256, 0, stream>>>(Qb, Kpb, Vpb, amask, attn);
  gemm_bt_k<float><<<dim3(32, 16), 256, 0, stream>>>(attn, wdT, out, 4096, 2048, 2048);
}

// Round 5
// 379.746 us; speedup vs baseline: 2.2921x; 1.1550x over previous
//
#include <hip/hip_runtime.h>
#include <stdint.h>

#define B_ 2
#define S_ 2048
#define HID_ 2048
#define H_ 16
#define D_ 128
#define LOG2E 1.44269504088896f

typedef __bf16 bf16;
typedef __bf16 bf16x8 __attribute__((ext_vector_type(8)));
typedef __bf16 bf16x4 __attribute__((ext_vector_type(4)));
typedef float floatx4 __attribute__((ext_vector_type(4)));

#define MFMA16(a, b, c) __builtin_amdgcn_mfma_f32_16x16x32_bf16(a, b, c, 0, 0, 0)

__device__ __forceinline__ void gload_lds16(const bf16* g, bf16* l) {
  __builtin_amdgcn_global_load_lds(
      (const __attribute__((address_space(1))) uint32_t*)g,
      (__attribute__((address_space(3))) uint32_t*)l, 16, 0, 0);
}

// ---------------- pack A: f32 row-major (M x K) -> packed bf16 fragments ----------------
// Ap[mb][kb][c(8)][l(64)][8] = A[mb*128 + c*16 + (l&15)][kb*32 + (l>>4)*8 + j]
__global__ __launch_bounds__(256) void pack_a_k(const float* __restrict__ in,
                                                bf16* __restrict__ out,
                                                int K, int nk) {
  int mb = blockIdx.x, kb = blockIdx.y;
  int t = threadIdx.x;
  int c = t >> 5, sub = t & 31;
  bf16* obase = out + (((size_t)mb * nk + kb) * 8 + c) * 512;
#pragma unroll
  for (int i = 0; i < 2; i++) {
    int l = sub * 2 + i;
    int row = mb * 128 + c * 16 + (l & 15);
    int col = kb * 32 + (l >> 4) * 8;
    const float* ip = in + (size_t)row * K + col;
    float4 a = *(const float4*)ip;
    float4 b2 = *(const float4*)(ip + 4);
    bf16x8 o;
    o[0] = (bf16)a.x; o[1] = (bf16)a.y; o[2] = (bf16)a.z; o[3] = (bf16)a.w;
    o[4] = (bf16)b2.x; o[5] = (bf16)b2.y; o[6] = (bf16)b2.z; o[7] = (bf16)b2.w;
    *(bf16x8*)(obase + l * 8) = o;
  }
}

// ---------------- pack B: W f32 row-major (K x N) -> packed bf16 fragments (transposed) ----
// Bp[nb][kb][c(8)][l(64)][8] = W[kb*32 + (l>>4)*8 + j][nb*128 + c*16 + (l&15)]
__global__ __launch_bounds__(256) void pack_b_k(const float* __restrict__ W,
                                                bf16* __restrict__ out,
                                                int N, int nk) {
  __shared__ float ftile[32][132];
  int nb = blockIdx.x, kb = blockIdx.y;
  int t = threadIdx.x;
#pragma unroll
  for (int p = 0; p < 4; p++) {
    int row = p * 8 + (t >> 5);
    int col = (t & 31) * 4;
    float4 v = *(const float4*)(W + (size_t)(kb * 32 + row) * N + nb * 128 + col);
    *(float4*)&ftile[row][col] = v;
  }
  __syncthreads();
  int c = t >> 5, sub = t & 31;
  bf16* obase = out + (((size_t)nb * nk + kb) * 8 + c) * 512;
#pragma unroll
  for (int i = 0; i < 2; i++) {
    int l = sub * 2 + i;
    int rbase = (l >> 4) * 8;
    int coln = c * 16 + (l & 15);
    bf16x8 o;
#pragma unroll
    for (int j = 0; j < 8; j++) o[j] = (bf16)ftile[rbase + j][coln];
    *(bf16x8*)(obase + l * 8) = o;
  }
}

// ---------------- GEMM on packed operands: dbuf LDS, 1 barrier/iter, conflict-free ----
template <typename OutT>
__global__ __launch_bounds__(256, 2) void gemm_p_k(const bf16* __restrict__ Ap,
                                                   const bf16* __restrict__ Bp,
                                                   OutT* __restrict__ C,
                                                   int N, int nk) {
  __shared__ __align__(16) bf16 stage[2][8192];  // [A 8 chunks][B 8 chunks] x 512
  const int t = threadIdx.x;
  const int w = t >> 6, l = t & 63;
  const int quad = l >> 4, ln = l & 15;
  const int wm = w >> 1, wn = w & 1;
  const int mb = blockIdx.x, nb = blockIdx.y;

  // wave w stages chunks gi = 4w..4w+3 (waves 0,1 -> A chunks 0..7; 2,3 -> B chunks 0..7)
  const bf16* sbase = (w < 2 ? Ap + ((size_t)mb * nk * 8 + w * 4) * 512
                             : Bp + ((size_t)nb * nk * 8 + (w - 2) * 4) * 512) + l * 8;
  bf16* dbase0 = stage[0] + w * 2048;
  bf16* dbase1 = stage[1] + w * 2048;

  floatx4 acc[4][4] = {};

#pragma unroll
  for (int i = 0; i < 4; i++) gload_lds16(sbase + i * 512, dbase0 + i * 512);

  for (int kb = 0; kb < nk; kb++) {
    __syncthreads();  // waits DMA issued last iter (covered by 16 MFMAs) + own ds_reads
    if (kb + 1 < nk) {
      const bf16* s = sbase + (size_t)(kb + 1) * 4096;
      bf16* d = ((kb + 1) & 1) ? dbase1 : dbase0;
#pragma unroll
      for (int i = 0; i < 4; i++) gload_lds16(s + i * 512, d + i * 512);
    }
    const bf16* cur = stage[kb & 1];
    bf16x8 af[4], bfr[4];
#pragma unroll
    for (int mt = 0; mt < 4; mt++)
      af[mt] = *(const bf16x8*)(cur + (wm * 4 + mt) * 512 + l * 8);
#pragma unroll
    for (int nt = 0; nt < 4; nt++)
      bfr[nt] = *(const bf16x8*)(cur + 4096 + (wn * 4 + nt) * 512 + l * 8);
#pragma unroll
    for (int mt = 0; mt < 4; mt++)
#pragma unroll
      for (int nt = 0; nt < 4; nt++)
        acc[mt][nt] = MFMA16(af[mt], bfr[nt], acc[mt][nt]);
  }

  const int m0 = mb * 128, n0 = nb * 128;
#pragma unroll
  for (int mt = 0; mt < 4; mt++)
#pragma unroll
    for (int nt = 0; nt < 4; nt++) {
      int row = m0 + wm * 64 + mt * 16 + quad * 4;
      int col = n0 + wn * 64 + nt * 16 + ln;
      OutT* cp = C + (size_t)row * N + col;
#pragma unroll
      for (int r = 0; r < 4; r++)
        cp[(size_t)r * N] = (OutT)acc[mt][nt][r];
    }
}

// ---------------- qkv split + xPos rotary + packed K/V layouts ----------------
__global__ __launch_bounds__(256) void qkv_transform_k(const bf16* __restrict__ qkv,
                                                       const int* __restrict__ pos_ids,
                                                       bf16* __restrict__ Q,
                                                       bf16* __restrict__ Kp,
                                                       bf16* __restrict__ Vp) {
  __shared__ __align__(16) bf16 vtile[128 * 72];
  const float QS = 0.08838834764831845f * LOG2E;  // 1/sqrt(128) * log2(e)
  int blk = blockIdx.x;
  int st = blk & 31;
  int h = (blk >> 5) & 15;
  int b = blk >> 9;
  int bh = b * H_ + h;
  int t = threadIdx.x;
  int sl = t >> 2, dg = t & 3;
  int s = st * 64 + sl;
  float tp = (float)pos_ids[b * S_ + s];

  const bf16* base = qkv + (size_t)(b * S_ + s) * (3 * HID_) + h * (3 * D_) + dg * 32;
  bf16 qv[32], kv[32], vv[32];
#pragma unroll
  for (int i = 0; i < 4; i++) ((bf16x8*)qv)[i] = *(const bf16x8*)(base + i * 8);
#pragma unroll
  for (int i = 0; i < 4; i++) ((bf16x8*)kv)[i] = *(const bf16x8*)(base + D_ + i * 8);
#pragma unroll
  for (int i = 0; i < 4; i++) ((bf16x8*)vv)[i] = *(const bf16x8*)(base + 2 * D_ + i * 8);

  if (dg == 0) {  // rotary covers dims 0..31 exactly
    float power = (tp - 1024.0f) * (1.0f / 512.0f);
#pragma unroll
    for (int i = 0; i < 16; i++) {
      float inv_freq = powf(10000.0f, -(float)i * (1.0f / 16.0f));
      float fr = tp * inv_freq;
      float cs = cosf(fr), sn = sinf(fr);
      float scl = ((float)(2 * i) + 12.8f) * (1.0f / 44.8f);
      float sc = powf(scl, power);
      float cq = cs * sc, sq = sn * sc;
      float ck = cs / sc, sk = sn / sc;
      float q1 = (float)qv[i], q2 = (float)qv[i + 16];
      float k1 = (float)kv[i], k2 = (float)kv[i + 16];
      qv[i] = (bf16)(q1 * cq - q2 * sq);
      qv[i + 16] = (bf16)(q2 * cq + q1 * sq);
      kv[i] = (bf16)(k1 * ck - k2 * sk);
      kv[i + 16] = (bf16)(k2 * ck + k1 * sk);
    }
  }
#pragma unroll
  for (int i = 0; i < 32; i++) qv[i] = (bf16)((float)qv[i] * QS);

  size_t qoff = (size_t)(bh * S_ + s) * D_ + dg * 32;
#pragma unroll
  for (int i = 0; i < 4; i++) *(bf16x8*)(Q + qoff + i * 8) = ((bf16x8*)qv)[i];

  {
    int mt = sl >> 4, lnq = sl & 15;
    bf16* kdst = Kp + (size_t)bh * (S_ * D_) + (size_t)st * 8192 + (mt * 4 + dg) * 512;
#pragma unroll
    for (int q = 0; q < 4; q++)
      *(bf16x8*)(kdst + (q * 16 + lnq) * 8) = ((bf16x8*)kv)[q];
  }

#pragma unroll
  for (int i = 0; i < 32; i++) vtile[(dg * 32 + i) * 72 + sl] = vv[i];
  __syncthreads();

  {
    int c = t >> 4, sub = t & 15;
    int dt = c >> 1, ksv = c & 1;
    bf16* vdst = Vp + (size_t)bh * (S_ * D_) + (size_t)st * 8192 + c * 512;
#pragma unroll
    for (int li = 0; li < 4; li++) {
      int lf = sub * 4 + li;
      int lq = lf >> 4, lln = lf & 15;
      bf16x8 tv = *(const bf16x8*)(vtile + (dt * 16 + lln) * 72 + ksv * 32 + lq * 8);
      *(bf16x8*)(vdst + lf * 8) = tv;
    }
  }
}

// ---------------- flash attention: lockstep waves + dbuf DMA; packed-A output ----------------
__global__ __launch_bounds__(256, 2) void flash_k(const bf16* __restrict__ Q,
                                                  const bf16* __restrict__ Kp,
                                                  const bf16* __restrict__ Vp,
                                                  const float* __restrict__ amask,
                                                  bf16* __restrict__ Ap2) {
  __shared__ __align__(16) bf16 stage[2][16384];
  __shared__ __align__(16) bf16 pbuf[4][16 * 72];
  int blk = blockIdx.x;
  int bh = blk & 31;
  int ab = blk >> 5;
  int b = bh >> 4, h = bh & 15;
  int t = threadIdx.x;
  int w = t >> 6, l = t & 63;
  int quad = l >> 4, ln = l & 15;

  const bf16* Kpb = Kp + (size_t)bh * (S_ * D_);
  const bf16* Vpb = Vp + (size_t)bh * (S_ * D_);
  const float* mbase = amask + (size_t)b * S_;
  bf16* pw = pbuf[w];

#pragma unroll
  for (int j = 0; j < 8; j++) {
    int gi = w * 8 + j;
    const bf16* src = (gi < 16 ? Kpb + gi * 512 : Vpb + (gi - 16) * 512) + l * 8;
    gload_lds16(src, stage[0] + gi * 512);
  }

  int it = 0;
#pragma unroll 1
  for (int phase = 0; phase < 2; phase++) {
    int a = phase ? (31 - ab) : ab;
    int strip = a * 4 + w;
    int qs = strip * 16;
    int T = a + 1;

    const bf16* Qp = Q + (size_t)(bh * S_ + qs + ln) * D_;
    bf16x8 qf[4];
#pragma unroll
    for (int ks = 0; ks < 4; ks++)
      qf[ks] = *(const bf16x8*)(Qp + ks * 32 + quad * 8);

    floatx4 oacc[8] = {};
    float m_i = -1e30f, l_i = 0.f;

#pragma unroll 1
    for (int kt = 0; kt < T; kt++, it++) {
      __syncthreads();
      const bf16* cur = stage[it & 1];
      if (it != 32) {
        int nkv = (kt + 1 < T) ? (kt + 1) : 0;
        bf16* nb = stage[(it + 1) & 1];
#pragma unroll
        for (int j = 0; j < 8; j++) {
          int gi = w * 8 + j;
          const bf16* src = (gi < 16 ? Kpb + (size_t)nkv * 8192 + gi * 512
                                     : Vpb + (size_t)nkv * 8192 + (gi - 16) * 512) + l * 8;
          gload_lds16(src, nb + gi * 512);
        }
      }
      int kv0 = kt * 64;

      floatx4 acc[4] = {};
#pragma unroll
      for (int ks = 0; ks < 4; ks++)
#pragma unroll
        for (int mt = 0; mt < 4; mt++) {
          bf16x8 kf = *(const bf16x8*)(cur + (mt * 4 + ks) * 512 + l * 8);
          acc[mt] = MFMA16(kf, qf[ks], acc[mt]);
        }

      floatx4 am4[4];
#pragma unroll
      for (int mt = 0; mt < 4; mt++)
        am4[mt] = *(const floatx4*)(mbase + kv0 + mt * 16 + quad * 4);

      bool diag = (kt == T - 1);
      int q = qs + ln;
      float v[4][4];
      float mx = -3.0e38f;
#pragma unroll
      for (int mt = 0; mt < 4; mt++)
#pragma unroll
        for (int r = 0; r < 4; r++) {
          float x = acc[mt][r] + am4[mt][r] * LOG2E;
          if (diag && (kv0 + mt * 16 + quad * 4 + r > q)) x = -3.0e38f;
          v[mt][r] = x;
          mx = fmaxf(mx, x);
        }
      mx = fmaxf(mx, __shfl_xor(mx, 16, 64));
      mx = fmaxf(mx, __shfl_xor(mx, 32, 64));
      float mnew = fmaxf(m_i, mx);
      float sum = 0.f;
      bf16x4 pk[4];
#pragma unroll
      for (int mt = 0; mt < 4; mt++)
#pragma unroll
        for (int r = 0; r < 4; r++) {
          float p = exp2f(v[mt][r] - mnew);
          sum += p;
          pk[mt][r] = (bf16)p;
        }
      sum += __shfl_xor(sum, 16, 64);
      sum += __shfl_xor(sum, 32, 64);
      float alpha = exp2f(m_i - mnew);
      l_i = l_i * alpha + sum;
      m_i = mnew;
#pragma unroll
      for (int dt = 0; dt < 8; dt++) oacc[dt] *= alpha;

#pragma unroll
      for (int mt = 0; mt < 4; mt++)
        *(bf16x4*)(pw + ln * 72 + mt * 16 + quad * 4) = pk[mt];

      const bf16* vcur = cur + 8192;
#pragma unroll
      for (int ks = 0; ks < 2; ks++) {
        bf16x8 pf = *(const bf16x8*)(pw + ln * 72 + ks * 32 + quad * 8);
#pragma unroll
        for (int dt = 0; dt < 8; dt++) {
          bf16x8 vf = *(const bf16x8*)(vcur + (dt * 2 + ks) * 512 + l * 8);
          oacc[dt] = MFMA16(vf, pf, oacc[dt]);
        }
      }
    }

    // epilogue: normalize + store directly in gemm2's packed-A layout
    // Ap2[mb][kb][c][l'][8] = attn[mb*128 + c*16 + (l'&15)][kb*32 + (l'>>4)*8 + j]
    float inv_l = 1.0f / l_i;
    int mrow = b * S_ + qs;  // multiple of 16
    int mb2 = mrow >> 7;
    int cc = (mrow >> 4) & 7;
    bf16* abase = Ap2 + ((size_t)mb2 * 64 * 8 + cc) * 512;
#pragma unroll
    for (int dt = 0; dt < 8; dt++) {
      bf16x4 ov;
#pragma unroll
      for (int r = 0; r < 4; r++) ov[r] = (bf16)(oacc[dt][r] * inv_l);
      int kb2 = h * 4 + (dt >> 1);
      int lp = ((dt & 1) * 2 + (quad >> 1)) * 16 + ln;
      *(bf16x4*)(abase + (size_t)kb2 * 4096 + lp * 8 + (quad & 1) * 4) = ov;
    }
  }
}

// ---------------- launch ----------------
extern "C" void kernel_launch(void* const* d_in, const int* in_sizes, int n_in,
                              void* d_out, int out_size, void* d_ws, size_t ws_size,
                              hipStream_t stream) {
  const float* hidden = (const float*)d_in[0];
  const float* amask = (const float*)d_in[1];
  const float* Wqkv = (const float*)d_in[2];
  const float* Wdense = (const float*)d_in[3];
  const int* posids = (const int*)d_in[4];
  float* out = (float*)d_out;
  char* ws = (char*)d_ws;

  // workspace (125,829,120 B, regions reused):
  //  [0,        8.39M)  Bp2 (Wdense packed)           — lives until gemm2
  //  [8.39M,   58.72M)  qkv bf16 (4096 x 6144)        — dead after qkv_transform
  //  [58.72M,  75.50M)  Ap1 (hidden packed) -> Ap2 (attn packed, written by flash)
  //  [75.50M, 100.66M)  Bp1 (Wqkv packed)   -> Q (written by qkv_transform) at 75.50M
  //  [92.27M, 109.05M)  Kp   (over Bp1 tail, written after gemm1)
  //  [109.05M,125.83M)  Vp
  bf16* Bp2 = (bf16*)(ws + 0);
  bf16* qkv = (bf16*)(ws + 8388608ull);
  bf16* Ap1 = (bf16*)(ws + 58720256ull);
  bf16* Ap2 = (bf16*)(ws + 58720256ull);
  bf16* Bp1 = (bf16*)(ws + 75497472ull);
  bf16* Qb = (bf16*)(ws + 75497472ull);
  bf16* Kpb = (bf16*)(ws + 92274688ull);
  bf16* Vpb = (bf16*)(ws + 109051904ull);

  pack_a_k<<<dim3(32, 64), 256, 0, stream>>>(hidden, Ap1, 2048, 64);
  pack_b_k<<<dim3(48, 64), 256, 0, stream>>>(Wqkv, Bp1, 6144, 64);
  pack_b_k<<<dim3(16, 64), 256, 0, stream>>>(Wdense, Bp2, 2048, 64);
  gemm_p_k<bf16><<<dim3(32, 48), 256, 0, stream>>>(Ap1, Bp1, qkv, 6144, 64);
  qkv_transform_k<<<1024, 256, 0, stream>>>(qkv, posids, Qb, Kpb, Vpb);
  flash_k<<<512, 256, 0, stream>>>(Qb, Kpb, Vpb, amask, Ap2);
  gemm_p_k<float><<<dim3(32, 16), 256, 0, stream>>>(Ap2, Bp2, out, 2048, 64);
}